// Round 5
// baseline (40499.039 us; speedup 1.0000x reference)
//
#include <hip/hip_runtime.h>
#include <stdint.h>

#define T_STEPS 4096
#define BATCH 32
#define HID 512
#define GROUPS 8            // blocks per batch
#define BLK_THREADS 1024    // 16 waves; 256 blocks = exactly 1/CU
#define NBLOCKS 256
#define BSLOT_DW 256                 // dwords per (slot,batch) h record: 8 groups x 32
#define SLOT_DW (BATCH * BSLOT_DW)   // dwords per parity slot (8192 = 32 KB)
#define TAG_STRIDE 16                // dwords per batch tag row (64B: no false sharing)

typedef _Float16 h2_t __attribute__((ext_vector_type(2)));

__device__ inline uint32_t pack_h2(float a, float b) {
  h2_t v;
  v.x = (_Float16)a;
  v.y = (_Float16)b;
  return __builtin_bit_cast(uint32_t, v);
}

__device__ inline float fdot2(uint32_t a, uint32_t b, float c) {
  return __builtin_amdgcn_fdot2(__builtin_bit_cast(h2_t, a),
                                __builtin_bit_cast(h2_t, b), c, false);
}

// vL1-ONLY invalidate. Plain buffer_inv (no sc bits) drops this CU's vector
// L1 and nothing else. This is the transport piece every failed round was
// missing: R6/7 (sc0 loads don't bypass vL1 -> stale spins), R11 (scalar K$
// path -> 16-wave s_dcache_inv storm through one scalar unit), R12 (sc1
// atomics -> MALL RTs, WRITE_SIZE x6.6), R13 (agent acquire fence ->
// buffer_inv sc1 -> per-step L2 flush, FETCH_SIZE x6). All traffic here
// stays inside the XCD's L2 (same-XCD guaranteed by the claim protocol).
__device__ inline void binv() {
  asm volatile("buffer_inv" ::: "memory");
}
// Vector-path dword load with completion inside the asm (consumers have a
// true data dependence -> cannot be hoisted above the wait; rule #18).
__device__ inline uint32_t vload_dw(const uint32_t* p) {
  uint32_t v;
  asm volatile("global_load_dword %0, %1, off\n\ts_waitcnt vmcnt(0)"
               : "=v"(v) : "v"(p) : "memory");
  return v;
}
// Fire-and-forget vector store (the tag "release"; data already drained).
__device__ inline void vstore_dw(uint32_t* p, uint32_t v) {
  asm volatile("global_store_dword %0, %1, off" :: "v"(p), "v"(v) : "memory");
}

__device__ inline float sigf(float x) { return 1.0f / (1.0f + __expf(-x)); }
__device__ inline float tanh_fast(float x) {
  float a = fabsf(x);
  float e = __expf(-2.0f * a);
  float r = (1.0f - e) / (1.0f + e);
  return copysignf(r, x);
}

// Round 14: R11's all-wave single-barrier structure, vector-path transport.
//   producer (wave 0): 64 plain 2B h-stores -> s_waitcnt vmcnt(0) ->
//                      global_store_dword tag = t+1.
//   consumers (all 16 waves): poll OWN producer group's tag with
//                      { buffer_inv; global_load_dword; vmcnt(0) } (~1 L2 RT
//                      per iteration, no scalar unit, no K$); then lane l
//                      loads dword (l&31) of the group's 32-dword slice and
//                      the matvec broadcasts it via v_readlane into
//                      v_dot2_f32_f16 src1 (SGPR operand — no LDS hop).
// Per-group polling preserves pipelining: a wave starts its matvec as soon
// as ITS producer published, independent of the other 7 groups.
// Freshness: producer drains data to L2 before the tag store; consumer's
// buffer_inv precedes the tag load, and the only vL1 fills of data lines
// come from post-check loads (nobody touches the record during polling), so
// a passed check implies data lines served at >= release time.
// Overwrite safety (parity buffers, tags monotonic): publishing t+2 into
// slot[t&1] requires passing the step-t+1 barrier, which requires all 16
// waves to have consumed slot[t&1] at t — unchanged proof from rounds 9-13.
__global__ __launch_bounds__(BLK_THREADS)
void lstm_vpoll(const float* __restrict__ x0,
                const float* __restrict__ W_ih,
                const float* __restrict__ W_hh,
                const float* __restrict__ b_ih,
                const float* __restrict__ b_hh,
                const float* __restrict__ W_lin,
                const float* __restrict__ b_lin,
                float* __restrict__ y,
                uint32_t* __restrict__ h_ex,   // [2][BATCH][GROUPS][32]
                uint32_t* __restrict__ tags,   // [BATCH][16] monotonic
                int* __restrict__ claim)       // [8][16] per-XCD claim
{
  __shared__ float x0_lds[T_STEPS];     // 16 KB: this batch's x0 column
  __shared__ float ylds[T_STEPS];       // 16 KB: per-block y partials
  __shared__ float gacc[2][256];        // parity-buffered gate accumulators
  __shared__ int s_bg;

  const int tid = threadIdx.x;

  // ---- claim a (batch, group) slot on THIS block's physical XCD ----
  if (tid == 0) {
    uint32_t xcc;
    asm volatile("s_getreg_b32 %0, hwreg(HW_REG_XCC_ID)" : "=s"(xcc));
    xcc &= 7;
    int slot = atomicAdd(claim + xcc * 16, 1);   // device-scope, one-time
    s_bg = (slot < 32) ? (int)(((4 * xcc + (slot >> 3)) << 3) | (slot & 7))
                       : -1;
  }
  __syncthreads();
  if (s_bg < 0) return;                  // surplus block
  const int b  = s_bg >> 3;              // batch (same XCD for all 8 groups)
  const int g  = s_bg & 7;               // group within batch
  const int u0 = g * 64;                 // first hidden unit owned
  const int wv = tid >> 6;               // wave 0..15
  const int rg = wv >> 3;                // row-group 0..1
  const int cs = wv & 7;                 // col-slice 0..7 == producer group
  const int l  = tid & 63;

  // ---- one-time: W_hh slice -> packed f16x2 -> VGPRs ----
  uint32_t w0[32], w1[32];
  {
    const int r0 = 128 * rg + l;
    const int r1 = r0 + 64;
    const int R0 = (r0 >> 6) * HID + u0 + (r0 & 63);  // gate*512 + unit
    const int R1 = (r1 >> 6) * HID + u0 + (r1 & 63);
    const float2* p0 = (const float2*)(W_hh + (size_t)R0 * HID + 64 * cs);
    const float2* p1 = (const float2*)(W_hh + (size_t)R1 * HID + 64 * cs);
#pragma unroll
    for (int k = 0; k < 32; ++k) {
      float2 a = p0[k], c = p1[k];
      w0[k] = pack_h2(a.x, a.y);
      w1[k] = pack_h2(c.x, c.y);
    }
  }
  // ---- one-time: x0 column, y partials, gacc ----
  for (int i = tid; i < T_STEPS; i += BLK_THREADS) {
    x0_lds[i] = x0[i * BATCH + b];
    ylds[i] = 0.f;
  }
  if (tid < 256) { gacc[0][tid] = 0.f; gacc[1][tid] = 0.f; }

  // ---- activation-lane constants (lanes 0..63 of wave 0) ----
  float c_state = 0.f;
  float wih_[4] = {0.f, 0.f, 0.f, 0.f}, bs_[4] = {0.f, 0.f, 0.f, 0.f};
  float wlin_u = 0.f, blin = 0.f;
  if (tid < 64) {
#pragma unroll
    for (int j = 0; j < 4; ++j) {
      int R = j * HID + u0 + tid;
      wih_[j] = W_ih[R];
      bs_[j] = b_ih[R] + b_hh[R];
    }
    wlin_u = W_lin[u0 + tid];
    blin = b_lin[0];
  }

  // ---- pointers ----
  uint32_t* tags_b = tags + b * TAG_STRIDE;
  uint32_t* tag_cs = tags_b + cs;                     // this wave's poll addr
  uint32_t* hrec[2] = { h_ex + (size_t)b * BSLOT_DW,
                        h_ex + SLOT_DW + (size_t)b * BSLOT_DW };
  uint32_t* pub01[2] = { hrec[0] + 32 * g, hrec[1] + 32 * g };

  __syncthreads();

  int dead = 0;
  for (int t = 0; t < T_STEPS; ++t) {
    const int sl = t & 1, ns = sl ^ 1;

    // ---- poll own producer group's tag (vector path, vL1-inv'd) ----
    if (!dead) {
      int guard = 0;
      for (;;) {
        binv();
        uint32_t tg = vload_dw(tag_cs);
        if ((int)tg >= t) break;
        if (++guard > (1 << 16)) { dead = 1; break; }  // anti-hang
      }
    }
    // ---- fetch slice: lane l holds dword (l&31) of group's 32 dwords ----
    uint32_t hval = vload_dw(hrec[sl] + 32 * cs + (l & 31));

    // ---- matvec: 2 rows x 64 cols per lane; h broadcast via v_readlane
    //      (v_dot2 src1 takes the SGPR directly; 4 independent acc chains) --
    float acc0a = 0.f, acc0b = 0.f, acc1a = 0.f, acc1b = 0.f;
#pragma unroll
    for (int k = 0; k < 32; k += 2) {
      uint32_t ha = __builtin_amdgcn_readlane(hval, k);
      uint32_t hb = __builtin_amdgcn_readlane(hval, k + 1);
      acc0a = fdot2(w0[k], ha, acc0a);
      acc1a = fdot2(w1[k], ha, acc1a);
      acc0b = fdot2(w0[k + 1], hb, acc0b);
      acc1b = fdot2(w1[k + 1], hb, acc1b);
    }
    atomicAdd(&gacc[sl][128 * rg + l], acc0a + acc0b);      // conflict-free
    atomicAdd(&gacc[sl][128 * rg + 64 + l], acc1a + acc1b);
    __syncthreads();   // the ONE block barrier per step

    // ---- activations + publish (wave 0, 64 lanes = 64 owned units) ----
    if (tid < 64) {
      const float xv = x0_lds[t];
      float gi = gacc[sl][tid]       + xv * wih_[0] + bs_[0];
      float gf = gacc[sl][tid + 64]  + xv * wih_[1] + bs_[1];
      float gg = gacc[sl][tid + 128] + xv * wih_[2] + bs_[2];
      float go = gacc[sl][tid + 192] + xv * wih_[3] + bs_[3];
      float si = sigf(gi), sf = sigf(gf), tg_ = tanh_fast(gg), so = sigf(go);
      c_state = sf * c_state + si * tg_;
      float h = so * tanh_fast(c_state);

      // publish: per-lane 2B store (coalesced 128B line), drain to L2,
      // then the vector tag store (the "release").
      ((_Float16*)pub01[ns])[tid] = (_Float16)h;
      asm volatile("s_waitcnt vmcnt(0)" ::: "memory");
      if (tid == 0) vstore_dw(tags_b + g, (uint32_t)(t + 1));

      // recycle gacc[sl] for step t+2 (ordering via the barrier chain)
      gacc[sl][tid] = 0.f;
      gacc[sl][tid + 64] = 0.f;
      gacc[sl][tid + 128] = 0.f;
      gacc[sl][tid + 192] = 0.f;

      // y partial (off critical path): fold 64 units -> ylds[t]
      float p = wlin_u * h;
#pragma unroll
      for (int m = 32; m >= 1; m >>= 1) p += __shfl_xor(p, m, 64);
      if (tid == 0) ylds[t] = p;
    }
  }

  // ---- drain: block partials -> global y (g==0 adds bias + residual) ----
  __syncthreads();
  for (int i = tid; i < T_STEPS; i += BLK_THREADS) {
    float val = ylds[i];
    if (g == 0) val += blin + x0_lds[i];
    unsafeAtomicAdd(&y[i * BATCH + b], val);
  }
}

extern "C" void kernel_launch(void* const* d_in, const int* in_sizes, int n_in,
                              void* d_out, int out_size, void* d_ws, size_t ws_size,
                              hipStream_t stream) {
  const float* x0    = (const float*)d_in[0];
  const float* W_ih  = (const float*)d_in[1];
  const float* W_hh  = (const float*)d_in[2];
  const float* b_ih  = (const float*)d_in[3];
  const float* b_hh  = (const float*)d_in[4];
  const float* W_lin = (const float*)d_in[5];
  const float* b_lin = (const float*)d_in[6];
  float* y = (float*)d_out;

  uint32_t* h_ex = (uint32_t*)d_ws;                    // 2 x 32 KB slots
  uint32_t* tags = h_ex + 2 * SLOT_DW;                 // 2 KB (64B/batch)
  int* claim     = (int*)(tags + BATCH * TAG_STRIDE);  // 512 B
  const size_t init_bytes =
      (size_t)(2 * SLOT_DW + BATCH * TAG_STRIDE) * sizeof(uint32_t)
      + 8 * 16 * sizeof(int);

  // memset 0: slot-0 h = 0 (== h0), tags = 0 ("h_0 available"), claim = 0
  (void)hipMemsetAsync(d_ws, 0, init_bytes, stream);
  (void)hipMemsetAsync(d_out, 0, (size_t)out_size * sizeof(float), stream);

  hipLaunchKernelGGL(lstm_vpoll, dim3(NBLOCKS), dim3(BLK_THREADS), 0, stream,
                     x0, W_ih, W_hh, b_ih, b_hh, W_lin, b_lin, y, h_ex, tags,
                     claim);
}

// Round 7
// 16661.960 us; speedup vs baseline: 2.4306x; 2.4306x over previous
//
#include <hip/hip_runtime.h>
#include <stdint.h>

#define T_STEPS 4096
#define BATCH 32
#define HID 512
#define GROUPS 8            // blocks per batch
#define BLK_THREADS 1024    // 16 waves; 256 blocks = exactly 1/CU
#define NBLOCKS 256
#define BSLOT_DW 256                 // dwords per (slot,batch) h record: 8 groups x 32
#define SLOT_DW (BATCH * BSLOT_DW)   // dwords per parity slot (8192 = 32 KB)
#define TAG_STRIDE 16                // one 64B line of tags per batch

typedef _Float16 h2_t __attribute__((ext_vector_type(2)));
typedef uint32_t u32x8 __attribute__((ext_vector_type(8)));
typedef uint32_t u32x16 __attribute__((ext_vector_type(16)));

__device__ inline uint32_t pack_h2(float a, float b) {
  h2_t v;
  v.x = (_Float16)a;
  v.y = (_Float16)b;
  return __builtin_bit_cast(uint32_t, v);
}

__device__ inline float fdot2(uint32_t a, uint32_t b, float c) {
  return __builtin_amdgcn_fdot2(__builtin_bit_cast(h2_t, a),
                                __builtin_bit_cast(h2_t, b), c, false);
}

// Launder a wave-uniform pointer into an SGPR-resident uint64 for "s" asm.
__device__ inline uint64_t uni64(const void* p) {
  uint32_t lo = __builtin_amdgcn_readfirstlane((uint32_t)(uintptr_t)p);
  uint32_t hi = __builtin_amdgcn_readfirstlane((uint32_t)((uintptr_t)p >> 32));
  return ((uint64_t)hi << 32) | lo;
}

// Scalar K$ invalidate — now issued by ONE wave per CU (wave 15), not 16.
// Scorecard that forced this design:
//   R9/R11 (16 waves x inv/iter):        14.5-15.0 ms  (inv broadcast storm)
//   R12 sc1 agent atomics:               29 ms (MALL RTs, WRITE x6.6)
//   R13 agent acquire fence per step:    31 ms (L2 flush, FETCH x6)
//   R14 buffer_inv per iteration:        40 ms (vL1 thrash, FETCH x4)
//   R15 pure atomic-RMW transport:       timeout (4096 pollers starve the
//                                        MALL RMW queues; producer release
//                                        never lands)
// R9 vs R11 differed 16x in scalar-load fusion but only 3% in time -> the
// INV count, not the load count, is the cost. This round cuts inv sources
// 16x while keeping the (correctness-proven) scalar transport.
__device__ inline void kinv() {
  asm volatile("s_dcache_inv" ::: "memory");
}
__device__ inline u32x8 sload8(uint64_t p) {
  u32x8 v;
  asm volatile("s_load_dwordx8 %0, %1, 0x0\n\ts_waitcnt lgkmcnt(0)"
               : "=&s"(v) : "s"(p) : "memory");
  return v;
}
__device__ inline void sload32(uint64_t p, u32x16* a, u32x16* b) {
  asm volatile("s_load_dwordx16 %0, %2, 0x0\n\t"
               "s_load_dwordx16 %1, %2, 0x40\n\t"
               "s_waitcnt lgkmcnt(0)"
               : "=&s"(*a), "=&s"(*b) : "s"(p) : "memory");
}

__device__ inline float sigf(float x) { return 1.0f / (1.0f + __expf(-x)); }
__device__ inline float tanh_fast(float x) {
  float a = fabsf(x);
  float e = __expf(-2.0f * a);
  float r = (1.0f - e) / (1.0f + e);
  return copysignf(r, x);
}

// Round 16: single-inv-wave scalar transport + LDS flag fan-out.
//   producer (wave 0): 64 plain 2B h-stores -> s_waitcnt vmcnt(0) -> plain
//                      volatile tag store (unchanged since R9).
//   poller  (wave 15): { s_dcache_inv; s_load_dwordx8 all 8 tags; mirror
//                      them into LDS hflag[] } until all >= t. ONE inv
//                      source per CU.
//   consumers (15 waves): spin on LDS hflag[cs] (per-group pipelining
//                      preserved, zero cache traffic), then fetch their
//                      32-dword slice with 2x s_load_dwordx16 — NO inv of
//                      their own.
// Freshness: consumer's data s_load at step t is preceded, in its CU's K$
// domain, by the poller's inv that OBSERVED tag>=t (which is after the
// producer's vmcnt(0) data drain). Data lines enter K$ only via post-flag
// loads, so any K$ hit is a post-release copy. Stale slot lines from step
// t-2 were invalidated by the poller's step-t-1/t polling invs (ordered by
// the block barrier).
// Overwrite safety (parity buffers, monotonic tags): publishing t+2 into
// slot[t&1] requires passing the step-t+1 barrier, which transitively
// requires every consumer block to have consumed slot[t&1] at step t —
// proof unchanged since R9.
__global__ __launch_bounds__(BLK_THREADS)
void lstm_onepoll(const float* __restrict__ x0,
                  const float* __restrict__ W_ih,
                  const float* __restrict__ W_hh,
                  const float* __restrict__ b_ih,
                  const float* __restrict__ b_hh,
                  const float* __restrict__ W_lin,
                  const float* __restrict__ b_lin,
                  float* __restrict__ y,
                  uint32_t* __restrict__ h_ex,   // [2][BATCH][GROUPS][32]
                  uint32_t* __restrict__ tags,   // [BATCH][16] monotonic
                  int* __restrict__ claim)       // [8][16] per-XCD claim
{
  __shared__ float x0_lds[T_STEPS];     // 16 KB: this batch's x0 column
  __shared__ float ylds[T_STEPS];       // 16 KB: per-block y partials
  __shared__ float gacc[2][256];        // parity-buffered gate accumulators
  __shared__ int hflag[8];              // LDS mirror of the 8 group tags
  __shared__ int s_bg;

  const int tid = threadIdx.x;

  // ---- claim a (batch, group) slot on THIS block's physical XCD ----
  if (tid == 0) {
    uint32_t xcc;
    asm volatile("s_getreg_b32 %0, hwreg(HW_REG_XCC_ID)" : "=s"(xcc));
    xcc &= 7;
    int slot = atomicAdd(claim + xcc * 16, 1);   // one-time
    s_bg = (slot < 32) ? (int)(((4 * xcc + (slot >> 3)) << 3) | (slot & 7))
                       : -1;
  }
  __syncthreads();
  if (s_bg < 0) return;                  // surplus block
  const int b  = s_bg >> 3;              // batch (same XCD for all 8 groups)
  const int g  = s_bg & 7;               // group within batch
  const int u0 = g * 64;                 // first hidden unit owned
  const int wv = tid >> 6;               // wave 0..15
  const int rg = wv >> 3;                // row-group 0..1
  const int cs = wv & 7;                 // col-slice 0..7 == producer group
  const int l  = tid & 63;

  // ---- one-time: W_hh slice -> packed f16x2 -> VGPRs ----
  uint32_t w0[32], w1[32];
  {
    const int r0 = 128 * rg + l;
    const int r1 = r0 + 64;
    const int R0 = (r0 >> 6) * HID + u0 + (r0 & 63);  // gate*512 + unit
    const int R1 = (r1 >> 6) * HID + u0 + (r1 & 63);
    const float2* p0 = (const float2*)(W_hh + (size_t)R0 * HID + 64 * cs);
    const float2* p1 = (const float2*)(W_hh + (size_t)R1 * HID + 64 * cs);
#pragma unroll
    for (int k = 0; k < 32; ++k) {
      float2 a = p0[k], c = p1[k];
      w0[k] = pack_h2(a.x, a.y);
      w1[k] = pack_h2(c.x, c.y);
    }
  }
  // ---- one-time: x0 column, y partials, gacc, flags ----
  for (int i = tid; i < T_STEPS; i += BLK_THREADS) {
    x0_lds[i] = x0[i * BATCH + b];
    ylds[i] = 0.f;
  }
  if (tid < 256) { gacc[0][tid] = 0.f; gacc[1][tid] = 0.f; }
  if (tid < 8) hflag[tid] = 0;          // tag 0 == "h_0 available"

  // ---- activation-lane constants (lanes 0..63 of wave 0) ----
  float c_state = 0.f;
  float wih_[4] = {0.f, 0.f, 0.f, 0.f}, bs_[4] = {0.f, 0.f, 0.f, 0.f};
  float wlin_u = 0.f, blin = 0.f;
  if (tid < 64) {
#pragma unroll
    for (int j = 0; j < 4; ++j) {
      int R = j * HID + u0 + tid;
      wih_[j] = W_ih[R];
      bs_[j] = b_ih[R] + b_hh[R];
    }
    wlin_u = W_lin[u0 + tid];
    blin = b_lin[0];
  }

  // ---- wave-uniform SGPR addresses ----
  uint32_t* tags_b = tags + b * TAG_STRIDE;
  const uint64_t tagu = uni64(tags_b);              // poller address
  uint32_t* hb0 = h_ex + (size_t)b * BSLOT_DW;
  const uint64_t dpu[2] = { uni64(hb0 + 32 * cs),
                            uni64(hb0 + SLOT_DW + 32 * cs) };
  uint32_t* pub01[2] = { hb0 + 32 * g, hb0 + SLOT_DW + 32 * g };

  __syncthreads();

  int dead = 0;
  for (int t = 0; t < T_STEPS; ++t) {
    const int sl = t & 1, ns = sl ^ 1;

    if (wv == 15) {
      // ---- the ONE inv-ing wave: poll all 8 tags, mirror into LDS ----
      if (!dead) {
        int guard = 0;
        for (;;) {
          kinv();
          u32x8 tg = sload8(tagu);
          if (l == 0) {
#pragma unroll
            for (int i = 0; i < 8; ++i)
              ((volatile int*)hflag)[i] = (int)tg[i];
          }
          bool ok = ((int)tg[0] >= t) & ((int)tg[1] >= t) &
                    ((int)tg[2] >= t) & ((int)tg[3] >= t) &
                    ((int)tg[4] >= t) & ((int)tg[5] >= t) &
                    ((int)tg[6] >= t) & ((int)tg[7] >= t);
          if (ok) break;
          if (++guard > (1 << 14)) { dead = 1; break; }  // anti-hang
          __builtin_amdgcn_s_sleep(1);
        }
        if (dead && l == 0) {            // release everyone, finish garbage
#pragma unroll
          for (int i = 0; i < 8; ++i)
            ((volatile int*)hflag)[i] = 0x7fffffff;
        }
      }
    } else {
      // ---- consumers: spin on own group's LDS flag (no cache traffic) ----
      int guard = 0;
      while (((volatile int*)hflag)[cs] < t) {
        if (++guard > (1 << 18)) break;  // anti-hang
        __builtin_amdgcn_s_sleep(1);
      }
    }

    // ---- fetch own 32-dword slice (scalar, NO inv; covered by poller's) ----
    u32x16 h0_, h1_;
    sload32(dpu[sl], &h0_, &h1_);

    // ---- matvec: 2 rows x 64 cols per lane; h uniform from SGPRs ----
    float acc0a = 0.f, acc0b = 0.f, acc1a = 0.f, acc1b = 0.f;
#pragma unroll
    for (int k = 0; k < 16; ++k) {
      acc0a = fdot2(w0[k], h0_[k], acc0a);
      acc1a = fdot2(w1[k], h0_[k], acc1a);
      acc0b = fdot2(w0[16 + k], h1_[k], acc0b);
      acc1b = fdot2(w1[16 + k], h1_[k], acc1b);
    }
    atomicAdd(&gacc[sl][128 * rg + l], acc0a + acc0b);      // conflict-free
    atomicAdd(&gacc[sl][128 * rg + 64 + l], acc1a + acc1b);
    __syncthreads();   // the ONE block barrier per step

    // ---- activations + publish (wave 0, 64 lanes = 64 owned units) ----
    if (tid < 64) {
      const float xv = x0_lds[t];
      float gi = gacc[sl][tid]       + xv * wih_[0] + bs_[0];
      float gf = gacc[sl][tid + 64]  + xv * wih_[1] + bs_[1];
      float gg = gacc[sl][tid + 128] + xv * wih_[2] + bs_[2];
      float go = gacc[sl][tid + 192] + xv * wih_[3] + bs_[3];
      float si = sigf(gi), sf = sigf(gf), tg_ = tanh_fast(gg), so = sigf(go);
      c_state = sf * c_state + si * tg_;
      float h = so * tanh_fast(c_state);

      // publish: per-lane 2B store (one coalesced 128B line) -> drain to L2
      // -> plain tag store (the "release"; proven since R9).
      ((_Float16*)pub01[ns])[tid] = (_Float16)h;
      asm volatile("s_waitcnt vmcnt(0)" ::: "memory");
      if (tid == 0) *(volatile uint32_t*)(tags_b + g) = (uint32_t)(t + 1);

      // recycle gacc[sl] for step t+2 (ordering via the barrier chain)
      gacc[sl][tid] = 0.f;
      gacc[sl][tid + 64] = 0.f;
      gacc[sl][tid + 128] = 0.f;
      gacc[sl][tid + 192] = 0.f;

      // y partial (off critical path): fold 64 units -> ylds[t]
      float p = wlin_u * h;
#pragma unroll
      for (int m = 32; m >= 1; m >>= 1) p += __shfl_xor(p, m, 64);
      if (tid == 0) ylds[t] = p;
    }
  }

  // ---- drain: block partials -> global y (g==0 adds bias + residual) ----
  __syncthreads();
  for (int i = tid; i < T_STEPS; i += BLK_THREADS) {
    float val = ylds[i];
    if (g == 0) val += blin + x0_lds[i];
    unsafeAtomicAdd(&y[i * BATCH + b], val);
  }
}

extern "C" void kernel_launch(void* const* d_in, const int* in_sizes, int n_in,
                              void* d_out, int out_size, void* d_ws, size_t ws_size,
                              hipStream_t stream) {
  const float* x0    = (const float*)d_in[0];
  const float* W_ih  = (const float*)d_in[1];
  const float* W_hh  = (const float*)d_in[2];
  const float* b_ih  = (const float*)d_in[3];
  const float* b_hh  = (const float*)d_in[4];
  const float* W_lin = (const float*)d_in[5];
  const float* b_lin = (const float*)d_in[6];
  float* y = (float*)d_out;

  uint32_t* h_ex = (uint32_t*)d_ws;                    // 2 x 32 KB slots
  uint32_t* tags = h_ex + 2 * SLOT_DW;                 // 2 KB (64B/batch)
  int* claim     = (int*)(tags + BATCH * TAG_STRIDE);  // 512 B
  const size_t init_bytes =
      (size_t)(2 * SLOT_DW + BATCH * TAG_STRIDE) * sizeof(uint32_t)
      + 8 * 16 * sizeof(int);

  // memset 0: slot-0 h = 0 (== h0), tags = 0 ("h_0 available"), claim = 0
  (void)hipMemsetAsync(d_ws, 0, init_bytes, stream);
  (void)hipMemsetAsync(d_out, 0, (size_t)out_size * sizeof(float), stream);

  hipLaunchKernelGGL(lstm_onepoll, dim3(NBLOCKS), dim3(BLK_THREADS), 0, stream,
                     x0, W_ih, W_hh, b_ih, b_hh, W_lin, b_lin, y, h_ex, tags,
                     claim);
}

// Round 8
// 15740.770 us; speedup vs baseline: 2.5729x; 1.0585x over previous
//
#include <hip/hip_runtime.h>
#include <stdint.h>

#define T_STEPS 4096
#define BATCH 32
#define HID 512
#define GROUPS 8            // blocks per batch
#define BLK_THREADS 1024    // 16 waves; 256 blocks = exactly 1/CU
#define NBLOCKS 256
#define BSLOT_DW 256                 // dwords per (slot,batch) h record: 8 groups x 32
#define SLOT_DW (BATCH * BSLOT_DW)   // dwords per parity slot (8192 = 32 KB)
#define TAG_STRIDE 16                // one 64B line of tags per batch

typedef _Float16 h2_t __attribute__((ext_vector_type(2)));
typedef uint32_t u32x8 __attribute__((ext_vector_type(8)));
typedef uint32_t u32x16 __attribute__((ext_vector_type(16)));

__device__ inline uint32_t pack_h2(float a, float b) {
  h2_t v;
  v.x = (_Float16)a;
  v.y = (_Float16)b;
  return __builtin_bit_cast(uint32_t, v);
}

__device__ inline float fdot2(uint32_t a, uint32_t b, float c) {
  return __builtin_amdgcn_fdot2(__builtin_bit_cast(h2_t, a),
                                __builtin_bit_cast(h2_t, b), c, false);
}

// Launder a wave-uniform pointer into an SGPR-resident uint64 for "s" asm.
__device__ inline uint64_t uni64(const void* p) {
  uint32_t lo = __builtin_amdgcn_readfirstlane((uint32_t)(uintptr_t)p);
  uint32_t hi = __builtin_amdgcn_readfirstlane((uint32_t)((uintptr_t)p >> 32));
  return ((uint64_t)hi << 32) | lo;
}

// Scalar K$ invalidate — issued by ONE wave per CU (wave 15).
// Transport scorecard:
//   R9/R11 (16 waves x inv/iter, PLAIN tag store): 14.5-15.0 ms, CLEAN
//       counters (FETCH 19 MB, WRITE 33 MB) — inv-storm-limited.
//   R12 sc1 agent atomics:     29 ms (MALL RTs, WRITE x6.6)
//   R13 agent fence per step:  31 ms (L2 flush, FETCH x6)
//   R14 buffer_inv per iter:   40 ms (vL1 thrash)
//   R15 pure atomic RMW:       timeout (MALL RMW queues)
//   R16 single-inv-wave + VOLATILE tag store: 16.7 ms, WRITE +61 MB
//       == 256 blocks x 4096 steps x 64 B -> volatile emits sc0/sc1
//       device-scope stores; every release went to the MALL and evicted
//       the L2 tag line; every poll read became a MALL RT. CONFOUNDED.
// Round 17 = R16 with the release restored to R9's PLAIN store (L2-
// resident). Clean test of the single-inv-wave design.
__device__ inline void kinv() {
  asm volatile("s_dcache_inv" ::: "memory");
}
__device__ inline u32x8 sload8(uint64_t p) {
  u32x8 v;
  asm volatile("s_load_dwordx8 %0, %1, 0x0\n\ts_waitcnt lgkmcnt(0)"
               : "=&s"(v) : "s"(p) : "memory");
  return v;
}
__device__ inline void sload32(uint64_t p, u32x16* a, u32x16* b) {
  asm volatile("s_load_dwordx16 %0, %2, 0x0\n\t"
               "s_load_dwordx16 %1, %2, 0x40\n\t"
               "s_waitcnt lgkmcnt(0)"
               : "=&s"(*a), "=&s"(*b) : "s"(p) : "memory");
}

__device__ inline float sigf(float x) { return 1.0f / (1.0f + __expf(-x)); }
__device__ inline float tanh_fast(float x) {
  float a = fabsf(x);
  float e = __expf(-2.0f * a);
  float r = (1.0f - e) / (1.0f + e);
  return copysignf(r, x);
}

// Round 17: single-inv-wave scalar transport + LDS flag fan-out + PLAIN
// tag release.
//   producer (wave 0): 64 plain 2B h-stores -> s_waitcnt vmcnt(0) -> PLAIN
//                      tag store (L2-resident; exactly R9/R11's release).
//   poller  (wave 15): { s_dcache_inv; s_load_dwordx8 all 8 tags; mirror
//                      into LDS hflag[] } until all >= t. ONE inv source
//                      per CU (vs 16 in R9/R11).
//   consumers (15 waves): spin on LDS hflag[cs] (per-group pipelining,
//                      zero cache traffic), then fetch their 32-dword slice
//                      with 2x s_load_dwordx16 — NO inv of their own.
// Freshness: consumer's data s_load at step t is preceded, in its CU's K$
// domain, by the poller's inv that OBSERVED tag>=t (which is after the
// producer's vmcnt(0) data drain). Data lines enter K$ only via post-flag
// loads, so any K$ hit is a post-release copy.
// Overwrite safety (parity buffers, monotonic tags): publishing t+2 into
// slot[t&1] requires passing the step-t+1 barrier, which transitively
// requires every consumer block to have consumed slot[t&1] at step t —
// proof unchanged since R9.
__global__ __launch_bounds__(BLK_THREADS)
void lstm_onepoll2(const float* __restrict__ x0,
                   const float* __restrict__ W_ih,
                   const float* __restrict__ W_hh,
                   const float* __restrict__ b_ih,
                   const float* __restrict__ b_hh,
                   const float* __restrict__ W_lin,
                   const float* __restrict__ b_lin,
                   float* __restrict__ y,
                   uint32_t* __restrict__ h_ex,   // [2][BATCH][GROUPS][32]
                   uint32_t* __restrict__ tags,   // [BATCH][16] monotonic
                   int* __restrict__ claim)       // [8][16] per-XCD claim
{
  __shared__ float x0_lds[T_STEPS];     // 16 KB: this batch's x0 column
  __shared__ float ylds[T_STEPS];       // 16 KB: per-block y partials
  __shared__ float gacc[2][256];        // parity-buffered gate accumulators
  __shared__ int hflag[8];              // LDS mirror of the 8 group tags
  __shared__ int s_bg;

  const int tid = threadIdx.x;

  // ---- claim a (batch, group) slot on THIS block's physical XCD ----
  if (tid == 0) {
    uint32_t xcc;
    asm volatile("s_getreg_b32 %0, hwreg(HW_REG_XCC_ID)" : "=s"(xcc));
    xcc &= 7;
    int slot = atomicAdd(claim + xcc * 16, 1);   // one-time
    s_bg = (slot < 32) ? (int)(((4 * xcc + (slot >> 3)) << 3) | (slot & 7))
                       : -1;
  }
  __syncthreads();
  if (s_bg < 0) return;                  // surplus block
  const int b  = s_bg >> 3;              // batch (same XCD for all 8 groups)
  const int g  = s_bg & 7;               // group within batch
  const int u0 = g * 64;                 // first hidden unit owned
  const int wv = tid >> 6;               // wave 0..15
  const int rg = wv >> 3;                // row-group 0..1
  const int cs = wv & 7;                 // col-slice 0..7 == producer group
  const int l  = tid & 63;

  // ---- one-time: W_hh slice -> packed f16x2 -> VGPRs ----
  uint32_t w0[32], w1[32];
  {
    const int r0 = 128 * rg + l;
    const int r1 = r0 + 64;
    const int R0 = (r0 >> 6) * HID + u0 + (r0 & 63);  // gate*512 + unit
    const int R1 = (r1 >> 6) * HID + u0 + (r1 & 63);
    const float2* p0 = (const float2*)(W_hh + (size_t)R0 * HID + 64 * cs);
    const float2* p1 = (const float2*)(W_hh + (size_t)R1 * HID + 64 * cs);
#pragma unroll
    for (int k = 0; k < 32; ++k) {
      float2 a = p0[k], c = p1[k];
      w0[k] = pack_h2(a.x, a.y);
      w1[k] = pack_h2(c.x, c.y);
    }
  }
  // ---- one-time: x0 column, y partials, gacc, flags ----
  for (int i = tid; i < T_STEPS; i += BLK_THREADS) {
    x0_lds[i] = x0[i * BATCH + b];
    ylds[i] = 0.f;
  }
  if (tid < 256) { gacc[0][tid] = 0.f; gacc[1][tid] = 0.f; }
  if (tid < 8) hflag[tid] = 0;          // tag 0 == "h_0 available"

  // ---- activation-lane constants (lanes 0..63 of wave 0) ----
  float c_state = 0.f;
  float wih_[4] = {0.f, 0.f, 0.f, 0.f}, bs_[4] = {0.f, 0.f, 0.f, 0.f};
  float wlin_u = 0.f, blin = 0.f;
  if (tid < 64) {
#pragma unroll
    for (int j = 0; j < 4; ++j) {
      int R = j * HID + u0 + tid;
      wih_[j] = W_ih[R];
      bs_[j] = b_ih[R] + b_hh[R];
    }
    wlin_u = W_lin[u0 + tid];
    blin = b_lin[0];
  }

  // ---- wave-uniform SGPR addresses ----
  uint32_t* tags_b = tags + b * TAG_STRIDE;
  const uint64_t tagu = uni64(tags_b);              // poller address
  uint32_t* hb0 = h_ex + (size_t)b * BSLOT_DW;
  const uint64_t dpu[2] = { uni64(hb0 + 32 * cs),
                            uni64(hb0 + SLOT_DW + 32 * cs) };
  uint32_t* pub01[2] = { hb0 + 32 * g, hb0 + SLOT_DW + 32 * g };

  __syncthreads();

  int dead = 0;
  for (int t = 0; t < T_STEPS; ++t) {
    const int sl = t & 1, ns = sl ^ 1;

    if (wv == 15) {
      // ---- the ONE inv-ing wave: poll all 8 tags, mirror into LDS ----
      if (!dead) {
        int guard = 0;
        for (;;) {
          kinv();
          u32x8 tg = sload8(tagu);
          if (l == 0) {
#pragma unroll
            for (int i = 0; i < 8; ++i)
              ((volatile int*)hflag)[i] = (int)tg[i];
          }
          bool ok = ((int)tg[0] >= t) & ((int)tg[1] >= t) &
                    ((int)tg[2] >= t) & ((int)tg[3] >= t) &
                    ((int)tg[4] >= t) & ((int)tg[5] >= t) &
                    ((int)tg[6] >= t) & ((int)tg[7] >= t);
          if (ok) break;
          if (++guard > (1 << 16)) { dead = 1; break; }  // anti-hang
          __builtin_amdgcn_s_sleep(1);
        }
        if (dead && l == 0) {            // release everyone, finish garbage
#pragma unroll
          for (int i = 0; i < 8; ++i)
            ((volatile int*)hflag)[i] = 0x7fffffff;
        }
      }
    } else {
      // ---- consumers: spin on own group's LDS flag (no cache traffic) ----
      int guard = 0;
      while (((volatile int*)hflag)[cs] < t) {
        if (++guard > (1 << 18)) break;  // anti-hang
        __builtin_amdgcn_s_sleep(1);
      }
    }

    // ---- fetch own 32-dword slice (scalar, NO inv; covered by poller's) ----
    u32x16 h0_, h1_;
    sload32(dpu[sl], &h0_, &h1_);

    // ---- matvec: 2 rows x 64 cols per lane; h uniform from SGPRs ----
    float acc0a = 0.f, acc0b = 0.f, acc1a = 0.f, acc1b = 0.f;
#pragma unroll
    for (int k = 0; k < 16; ++k) {
      acc0a = fdot2(w0[k], h0_[k], acc0a);
      acc1a = fdot2(w1[k], h0_[k], acc1a);
      acc0b = fdot2(w0[16 + k], h1_[k], acc0b);
      acc1b = fdot2(w1[16 + k], h1_[k], acc1b);
    }
    atomicAdd(&gacc[sl][128 * rg + l], acc0a + acc0b);      // conflict-free
    atomicAdd(&gacc[sl][128 * rg + 64 + l], acc1a + acc1b);
    __syncthreads();   // the ONE block barrier per step

    // ---- activations + publish (wave 0, 64 lanes = 64 owned units) ----
    if (tid < 64) {
      const float xv = x0_lds[t];
      float gi = gacc[sl][tid]       + xv * wih_[0] + bs_[0];
      float gf = gacc[sl][tid + 64]  + xv * wih_[1] + bs_[1];
      float gg = gacc[sl][tid + 128] + xv * wih_[2] + bs_[2];
      float go = gacc[sl][tid + 192] + xv * wih_[3] + bs_[3];
      float si = sigf(gi), sf = sigf(gf), tg_ = tanh_fast(gg), so = sigf(go);
      c_state = sf * c_state + si * tg_;
      float h = so * tanh_fast(c_state);

      // publish: per-lane 2B store (one coalesced 128B line) -> drain to L2
      // -> PLAIN tag store (R9's proven release; volatile would emit
      // device-scope sc bits and bounce the line to the MALL — R16's bug).
      ((_Float16*)pub01[ns])[tid] = (_Float16)h;
      asm volatile("s_waitcnt vmcnt(0)" ::: "memory");
      if (tid == 0) tags_b[g] = (uint32_t)(t + 1);

      // recycle gacc[sl] for step t+2 (ordering via the barrier chain)
      gacc[sl][tid] = 0.f;
      gacc[sl][tid + 64] = 0.f;
      gacc[sl][tid + 128] = 0.f;
      gacc[sl][tid + 192] = 0.f;

      // y partial (off critical path): fold 64 units -> ylds[t]
      float p = wlin_u * h;
#pragma unroll
      for (int m = 32; m >= 1; m >>= 1) p += __shfl_xor(p, m, 64);
      if (tid == 0) ylds[t] = p;
    }
  }

  // ---- drain: block partials -> global y (g==0 adds bias + residual) ----
  __syncthreads();
  for (int i = tid; i < T_STEPS; i += BLK_THREADS) {
    float val = ylds[i];
    if (g == 0) val += blin + x0_lds[i];
    unsafeAtomicAdd(&y[i * BATCH + b], val);
  }
}

extern "C" void kernel_launch(void* const* d_in, const int* in_sizes, int n_in,
                              void* d_out, int out_size, void* d_ws, size_t ws_size,
                              hipStream_t stream) {
  const float* x0    = (const float*)d_in[0];
  const float* W_ih  = (const float*)d_in[1];
  const float* W_hh  = (const float*)d_in[2];
  const float* b_ih  = (const float*)d_in[3];
  const float* b_hh  = (const float*)d_in[4];
  const float* W_lin = (const float*)d_in[5];
  const float* b_lin = (const float*)d_in[6];
  float* y = (float*)d_out;

  uint32_t* h_ex = (uint32_t*)d_ws;                    // 2 x 32 KB slots
  uint32_t* tags = h_ex + 2 * SLOT_DW;                 // 2 KB (64B/batch)
  int* claim     = (int*)(tags + BATCH * TAG_STRIDE);  // 512 B
  const size_t init_bytes =
      (size_t)(2 * SLOT_DW + BATCH * TAG_STRIDE) * sizeof(uint32_t)
      + 8 * 16 * sizeof(int);

  // memset 0: slot-0 h = 0 (== h0), tags = 0 ("h_0 available"), claim = 0
  (void)hipMemsetAsync(d_ws, 0, init_bytes, stream);
  (void)hipMemsetAsync(d_out, 0, (size_t)out_size * sizeof(float), stream);

  hipLaunchKernelGGL(lstm_onepoll2, dim3(NBLOCKS), dim3(BLK_THREADS), 0, stream,
                     x0, W_ih, W_hh, b_ih, b_hh, W_lin, b_lin, y, h_ex, tags,
                     claim);
}